// Round 5
// baseline (325.888 us; speedup 1.0000x reference)
//
#include <hip/hip_runtime.h>
#include <stdint.h>

// HashGrid encode, instant-ngp/tcnn defaults, Smoothstep interpolation.
// 16 levels, F=2, T=2^19, base_res=16, per_level_scale=2.0, 2D input.
// Levels 0..5 dense (res=16<<l, res^2 <= T), levels 6..15 hashed (4 MiB each).
//
// Round 5 (= round 4 with compile fix): 1 pt/thread; __launch_bounds__(256,4)
// so the 32-float accumulator stays in VGPRs (rounds 1/3 spilled: VGPR=36/48,
// +64-128 MB scratch traffic, occupancy 28%). Level phasing via per-block
// __syncthreads between hashed levels keeps the active 4 MiB table
// L2-resident per XCD. Nontemporal output stores keep the 64 MB output
// stream from evicting the phased table. Nontemporal builtins require native
// clang vector types, not HIP_vector_type -> ext_vector_type casts.

#define HG_LEVELS 16
#define HG_T (1u << 19)
#define HG_PRIME1 2654435761u

typedef float vfloat2 __attribute__((ext_vector_type(2)));
typedef float vfloat4 __attribute__((ext_vector_type(4)));

__global__ __launch_bounds__(256, 4) void hashgrid_encode5_kernel(
    const float* __restrict__ x,        // [N][2] points in [-1,1]^2
    const float* __restrict__ table,    // [16][T][2]
    float* __restrict__ out,            // [N][32]
    int npts)
{
    int i = blockIdx.x * blockDim.x + threadIdx.x;
    // clamp instead of early-return: keeps __syncthreads() uniform
    if (i >= npts) i = npts - 1;

    vfloat2 xi = __builtin_nontemporal_load((const vfloat2*)(x + 2 * (size_t)i));
    float x0 = xi.x * 0.5f + 0.5f;
    float x1 = xi.y * 0.5f + 0.5f;

    float acc[2 * HG_LEVELS];

#pragma unroll
    for (int l = 0; l < HG_LEVELS; ++l) {
        const int res = 16 << l;                   // = ceil(scale)+1, exact
        const float scale = (float)res - 1.0f;     // exactly representable
        float p0 = x0 * scale + 0.5f;
        float p1 = x1 * scale + 0.5f;
        float g0 = floorf(p0);
        float g1 = floorf(p1);
        float fr0 = p0 - g0;
        float fr1 = p1 - g1;
        uint32_t c0 = (uint32_t)(int)g0;           // pos >= 0.5 so pg >= 0
        uint32_t c1 = (uint32_t)(int)g1;
        float w0 = fr0 * fr0 * (3.0f - 2.0f * fr0);   // smoothstep
        float w1 = fr1 * fr1 * (3.0f - 2.0f * fr1);

        uint32_t i00, i10, i01, i11;
        if (l <= 5) {
            const uint32_t mask = (uint32_t)res * (uint32_t)res - 1u;  // pow2
            uint32_t b0 = c1 * (uint32_t)res;
            uint32_t b1 = (c1 + 1u) * (uint32_t)res;
            i00 = (c0 + b0) & mask;
            i10 = (c0 + 1u + b0) & mask;
            i01 = (c0 + b1) & mask;
            i11 = (c0 + 1u + b1) & mask;
        } else {
            uint32_t h0 = c1 * HG_PRIME1;
            uint32_t h1 = (c1 + 1u) * HG_PRIME1;
            i00 = (c0 ^ h0) & (HG_T - 1u);
            i10 = ((c0 + 1u) ^ h0) & (HG_T - 1u);
            i01 = (c0 ^ h1) & (HG_T - 1u);
            i11 = ((c0 + 1u) ^ h1) & (HG_T - 1u);
        }

        const float2* tl = (const float2*)(table + (size_t)l * (size_t)HG_T * 2u);
        float2 f00 = tl[i00];
        float2 f10 = tl[i10];
        float2 f01 = tl[i01];
        float2 f11 = tl[i11];

        float w00 = (1.0f - w0) * (1.0f - w1);
        float w10 = w0 * (1.0f - w1);
        float w01 = (1.0f - w0) * w1;
        float w11 = w0 * w1;

        acc[2 * l + 0] = w00 * f00.x + w10 * f10.x + w01 * f01.x + w11 * f11.x;
        acc[2 * l + 1] = w00 * f00.y + w10 * f10.y + w01 * f01.y + w11 * f11.y;

        // level phasing: keep the block's waves on the same hashed level so
        // the active 4 MiB table stays resident in each XCD's L2
        if (l >= 5 && l < HG_LEVELS - 1) __syncthreads();
    }

    // one 128B row per thread, 8x float4 nontemporal stores (don't pollute L2)
    float* o = out + (size_t)i * (2 * HG_LEVELS);
#pragma unroll
    for (int j = 0; j < 8; ++j) {
        vfloat4 v = { acc[4 * j + 0], acc[4 * j + 1],
                      acc[4 * j + 2], acc[4 * j + 3] };
        __builtin_nontemporal_store(v, (vfloat4*)(o + 4 * j));
    }
}

extern "C" void kernel_launch(void* const* d_in, const int* in_sizes, int n_in,
                              void* d_out, int out_size, void* d_ws, size_t ws_size,
                              hipStream_t stream) {
    const float* x = (const float*)d_in[0];
    const float* table = (const float*)d_in[1];
    float* out = (float*)d_out;

    int npts = in_sizes[0] / 2;          // 524288
    int block = 256;
    int grid = (npts + block - 1) / block;   // 2048
    hashgrid_encode5_kernel<<<grid, block, 0, stream>>>(x, table, out, npts);
}

// Round 6
// 268.629 us; speedup vs baseline: 1.2132x; 1.2132x over previous
//
#include <hip/hip_runtime.h>
#include <stdint.h>

// HashGrid encode, instant-ngp/tcnn defaults, Smoothstep interpolation.
// 16 levels, F=2, T=2^19, base_res=16, per_level_scale=2.0, 2D input.
// Levels 0..5 dense (res=16<<l, res^2 <= T), levels 6..15 hashed (4 MiB each).
//
// Round 6 = round 3's structure (2 pts/thread, level phasing) + round 5's
// spill fix (__launch_bounds__(256,4): VGPR cap 128, the 64 acc floats stay
// in registers; rounds 1/3 spilled at VGPR=36/48 -> scratch traffic) and
// PLAIN stores (round 5's nontemporal stores amplified WRITE 131->230 MB:
// 16B partial-line flushes defeat L2 write-combining).

#define HG_LEVELS 16
#define HG_T (1u << 19)
#define HG_PRIME1 2654435761u

__device__ __forceinline__ void level_setup(float x0, float x1, int l,
                                            uint32_t idx[4], float w[4])
{
    const int res = 16 << l;                   // = ceil(scale)+1, exact
    const float scale = (float)res - 1.0f;     // exactly representable
    float p0 = x0 * scale + 0.5f;
    float p1 = x1 * scale + 0.5f;
    float g0 = floorf(p0);
    float g1 = floorf(p1);
    float fr0 = p0 - g0;
    float fr1 = p1 - g1;
    uint32_t c0 = (uint32_t)(int)g0;           // pos >= 0.5 so pg >= 0
    uint32_t c1 = (uint32_t)(int)g1;
    float w0 = fr0 * fr0 * (3.0f - 2.0f * fr0);   // smoothstep
    float w1 = fr1 * fr1 * (3.0f - 2.0f * fr1);

    if (l <= 5) {
        const uint32_t mask = (uint32_t)res * (uint32_t)res - 1u;  // pow2
        uint32_t b0 = c1 * (uint32_t)res;
        uint32_t b1 = (c1 + 1u) * (uint32_t)res;
        idx[0] = (c0 + b0) & mask;
        idx[1] = (c0 + 1u + b0) & mask;
        idx[2] = (c0 + b1) & mask;
        idx[3] = (c0 + 1u + b1) & mask;
    } else {
        uint32_t h0 = c1 * HG_PRIME1;
        uint32_t h1 = (c1 + 1u) * HG_PRIME1;
        idx[0] = (c0 ^ h0) & (HG_T - 1u);
        idx[1] = ((c0 + 1u) ^ h0) & (HG_T - 1u);
        idx[2] = (c0 ^ h1) & (HG_T - 1u);
        idx[3] = ((c0 + 1u) ^ h1) & (HG_T - 1u);
    }
    w[0] = (1.0f - w0) * (1.0f - w1);
    w[1] = w0 * (1.0f - w1);
    w[2] = (1.0f - w0) * w1;
    w[3] = w0 * w1;
}

__global__ __launch_bounds__(256, 4) void hashgrid_encode6_kernel(
    const float4* __restrict__ x,       // [npairs] = two points (x0,y0,x1,y1)
    const float* __restrict__ table,    // [16][T][2]
    float* __restrict__ out,            // [2*npairs][32]
    int npairs)
{
    int t = blockIdx.x * blockDim.x + threadIdx.x;
    // clamp instead of early-return: keeps __syncthreads() uniform
    if (t >= npairs) t = npairs - 1;

    float4 xp = x[t];
    float a0 = xp.x * 0.5f + 0.5f;      // point A in [0,1]
    float a1 = xp.y * 0.5f + 0.5f;
    float b0 = xp.z * 0.5f + 0.5f;      // point B
    float b1 = xp.w * 0.5f + 0.5f;

    float accA[2 * HG_LEVELS];
    float accB[2 * HG_LEVELS];

#pragma unroll
    for (int l = 0; l < HG_LEVELS; ++l) {
        uint32_t ia[4], ib[4];
        float wa[4], wb[4];
        level_setup(a0, a1, l, ia, wa);
        level_setup(b0, b1, l, ib, wb);

        const float2* tl = (const float2*)(table + (size_t)l * (size_t)HG_T * 2u);
        float2 fa[4], fb[4];
#pragma unroll
        for (int c = 0; c < 4; ++c) fa[c] = tl[ia[c]];
#pragma unroll
        for (int c = 0; c < 4; ++c) fb[c] = tl[ib[c]];

        float sAx = 0.f, sAy = 0.f, sBx = 0.f, sBy = 0.f;
#pragma unroll
        for (int c = 0; c < 4; ++c) {
            sAx += wa[c] * fa[c].x;
            sAy += wa[c] * fa[c].y;
            sBx += wb[c] * fb[c].x;
            sBy += wb[c] * fb[c].y;
        }
        accA[2 * l + 0] = sAx;
        accA[2 * l + 1] = sAy;
        accB[2 * l + 0] = sBx;
        accB[2 * l + 1] = sBy;

        // level phasing: keep the block's waves on the same hashed level so
        // the active 4 MiB table stays resident in each XCD's L2
        if (l >= 5 && l < HG_LEVELS - 1) __syncthreads();
    }

    // two full 128B rows per thread; plain float4 stores merge in L2
    float4* oA = (float4*)(out + (size_t)(2 * t + 0) * (2 * HG_LEVELS));
    float4* oB = (float4*)(out + (size_t)(2 * t + 1) * (2 * HG_LEVELS));
#pragma unroll
    for (int j = 0; j < 8; ++j)
        oA[j] = make_float4(accA[4 * j + 0], accA[4 * j + 1],
                            accA[4 * j + 2], accA[4 * j + 3]);
#pragma unroll
    for (int j = 0; j < 8; ++j)
        oB[j] = make_float4(accB[4 * j + 0], accB[4 * j + 1],
                            accB[4 * j + 2], accB[4 * j + 3]);
}

extern "C" void kernel_launch(void* const* d_in, const int* in_sizes, int n_in,
                              void* d_out, int out_size, void* d_ws, size_t ws_size,
                              hipStream_t stream) {
    const float4* x = (const float4*)d_in[0];
    const float* table = (const float*)d_in[1];
    float* out = (float*)d_out;

    int npts = in_sizes[0] / 2;          // 524288
    int npairs = npts / 2;               // 262144
    int block = 256;
    int grid = (npairs + block - 1) / block;   // 1024
    hashgrid_encode6_kernel<<<grid, block, 0, stream>>>(x, table, out, npairs);
}

// Round 7
// 263.600 us; speedup vs baseline: 1.2363x; 1.0191x over previous
//
#include <hip/hip_runtime.h>
#include <stdint.h>

// HashGrid encode, instant-ngp/tcnn defaults, Smoothstep interpolation.
// 16 levels, F=2, T=2^19, base_res=16, per_level_scale=2.0, 2D input.
// Levels 0..5 dense (res=16<<l, res^2 <= T), levels 6..15 hashed (4 MiB each).
//
// Round 7: level-major two-kernel scheme.
//  K1: block = (level, 512-point chunk); bid&7 selects XCD, level = xcd or
//      xcd+8 -> each level's 4 MiB table is resident in exactly ONE XCD's L2
//      (kills the x8 table replication that dominated FETCH). Tiny per-thread
//      state -> no spills (rounds 1/3/6 spilled the 32/64-float acc row).
//      Output to level-major scratch [16][N][2] in d_ws: per-block 4 KB
//      contiguous NT stores (full cache lines -> no round-5 partial-line
//      amplification); x loads NT; table gathers plain (want L2 residency).
//  K2: transpose scratch -> out[N][32]; coalesced, plain stores merge in L2.
// Fallback to the round-6 single kernel if ws_size < 64 MB.

#define HG_LEVELS 16
#define HG_T (1u << 19)
#define HG_PRIME1 2654435761u

typedef float vfloat2 __attribute__((ext_vector_type(2)));
typedef float vfloat4 __attribute__((ext_vector_type(4)));

// ---------------- K1: level-major gather ----------------
__global__ __launch_bounds__(256) void hg_gather_kernel(
    const float* __restrict__ x,        // [N][2] in [-1,1]
    const float* __restrict__ table,    // [16][T][2]
    float* __restrict__ scratch,        // [16][N][2]
    int npts, int CH)                   // CH = chunks per level
{
    int bid = blockIdx.x;
    int xcd = bid & 7;
    int slot = bid >> 3;
    int level = (slot < CH) ? xcd : xcd + 8;
    int chunk = (slot < CH) ? slot : slot - CH;

    int p0 = chunk * 512 + 2 * (int)threadIdx.x;   // this thread: points p0, p0+1
    if (p0 + 1 >= npts) p0 = npts - 2;             // benign duplicate on tail

    vfloat4 xp = __builtin_nontemporal_load((const vfloat4*)(x + 2 * (size_t)p0));
    float a0 = xp.x * 0.5f + 0.5f;
    float a1 = xp.y * 0.5f + 0.5f;
    float b0 = xp.z * 0.5f + 0.5f;
    float b1 = xp.w * 0.5f + 0.5f;

    const int res = 16 << level;                 // = ceil(scale)+1, exact
    const float scale = (float)res - 1.0f;       // exactly representable
    const bool dense = (level <= 5);
    const uint32_t dmask = (uint32_t)res * (uint32_t)res - 1u;  // pow2 when dense

    // point A
    float pA0 = a0 * scale + 0.5f, pA1 = a1 * scale + 0.5f;
    float gA0 = floorf(pA0), gA1 = floorf(pA1);
    float fA0 = pA0 - gA0, fA1 = pA1 - gA1;
    uint32_t cA0 = (uint32_t)(int)gA0, cA1 = (uint32_t)(int)gA1;
    float wA0 = fA0 * fA0 * (3.0f - 2.0f * fA0);
    float wA1 = fA1 * fA1 * (3.0f - 2.0f * fA1);
    // point B
    float pB0 = b0 * scale + 0.5f, pB1 = b1 * scale + 0.5f;
    float gB0 = floorf(pB0), gB1 = floorf(pB1);
    float fB0 = pB0 - gB0, fB1 = pB1 - gB1;
    uint32_t cB0 = (uint32_t)(int)gB0, cB1 = (uint32_t)(int)gB1;
    float wB0 = fB0 * fB0 * (3.0f - 2.0f * fB0);
    float wB1 = fB1 * fB1 * (3.0f - 2.0f * fB1);

    uint32_t iA[4], iB[4];
    if (dense) {
        uint32_t bA0 = cA1 * (uint32_t)res, bA1 = (cA1 + 1u) * (uint32_t)res;
        iA[0] = (cA0 + bA0) & dmask;  iA[1] = (cA0 + 1u + bA0) & dmask;
        iA[2] = (cA0 + bA1) & dmask;  iA[3] = (cA0 + 1u + bA1) & dmask;
        uint32_t bB0 = cB1 * (uint32_t)res, bB1 = (cB1 + 1u) * (uint32_t)res;
        iB[0] = (cB0 + bB0) & dmask;  iB[1] = (cB0 + 1u + bB0) & dmask;
        iB[2] = (cB0 + bB1) & dmask;  iB[3] = (cB0 + 1u + bB1) & dmask;
    } else {
        uint32_t hA0 = cA1 * HG_PRIME1, hA1 = (cA1 + 1u) * HG_PRIME1;
        iA[0] = (cA0 ^ hA0) & (HG_T - 1u);  iA[1] = ((cA0 + 1u) ^ hA0) & (HG_T - 1u);
        iA[2] = (cA0 ^ hA1) & (HG_T - 1u);  iA[3] = ((cA0 + 1u) ^ hA1) & (HG_T - 1u);
        uint32_t hB0 = cB1 * HG_PRIME1, hB1 = (cB1 + 1u) * HG_PRIME1;
        iB[0] = (cB0 ^ hB0) & (HG_T - 1u);  iB[1] = ((cB0 + 1u) ^ hB0) & (HG_T - 1u);
        iB[2] = (cB0 ^ hB1) & (HG_T - 1u);  iB[3] = ((cB0 + 1u) ^ hB1) & (HG_T - 1u);
    }

    const float2* tl = (const float2*)(table + (size_t)level * (size_t)HG_T * 2u);
    float2 fAv[4], fBv[4];
#pragma unroll
    for (int c = 0; c < 4; ++c) fAv[c] = tl[iA[c]];
#pragma unroll
    for (int c = 0; c < 4; ++c) fBv[c] = tl[iB[c]];

    float wwA[4] = { (1.0f - wA0) * (1.0f - wA1), wA0 * (1.0f - wA1),
                     (1.0f - wA0) * wA1,          wA0 * wA1 };
    float wwB[4] = { (1.0f - wB0) * (1.0f - wB1), wB0 * (1.0f - wB1),
                     (1.0f - wB0) * wB1,          wB0 * wB1 };

    float sAx = 0.f, sAy = 0.f, sBx = 0.f, sBy = 0.f;
#pragma unroll
    for (int c = 0; c < 4; ++c) {
        sAx += wwA[c] * fAv[c].x;  sAy += wwA[c] * fAv[c].y;
        sBx += wwB[c] * fBv[c].x;  sBy += wwB[c] * fBv[c].y;
    }

    // scratch[level][p0..p0+1][2] : 16B contiguous per thread, 4KB per block
    vfloat4 v = { sAx, sAy, sBx, sBy };
    __builtin_nontemporal_store(
        v, (vfloat4*)(scratch + ((size_t)level * (size_t)npts + (size_t)p0) * 2u));
}

// ---------------- K2: transpose scratch -> out ----------------
__global__ __launch_bounds__(256) void hg_transpose_kernel(
    const float* __restrict__ scratch,  // [16][N][2]
    float* __restrict__ out,            // [N][32]
    int npts)
{
    int p0 = blockIdx.x * 512 + 2 * (int)threadIdx.x;
    if (p0 + 1 >= npts) p0 = npts - 2;

    float* o0 = out + (size_t)p0 * 32u;
    float* o1 = o0 + 32u;

#pragma unroll
    for (int j = 0; j < 8; ++j) {
        // levels 2j and 2j+1, points p0 and p0+1 (16B contiguous loads)
        vfloat4 a = __builtin_nontemporal_load(
            (const vfloat4*)(scratch + ((size_t)(2 * j) * (size_t)npts + (size_t)p0) * 2u));
        vfloat4 b = __builtin_nontemporal_load(
            (const vfloat4*)(scratch + ((size_t)(2 * j + 1) * (size_t)npts + (size_t)p0) * 2u));
        vfloat4 r0 = { a.x, a.y, b.x, b.y };   // point p0, features 4j..4j+3
        vfloat4 r1 = { a.z, a.w, b.z, b.w };   // point p0+1
        *(vfloat4*)(o0 + 4 * j) = r0;          // plain stores: L2 merges rows
        *(vfloat4*)(o1 + 4 * j) = r1;
    }
}

// ---------------- Fallback (round-6 style, known-good 184us) ----------------
__global__ __launch_bounds__(256) void hg_fallback_kernel(
    const float4* __restrict__ x, const float* __restrict__ table,
    float* __restrict__ out, int npairs)
{
    int t = blockIdx.x * blockDim.x + threadIdx.x;
    if (t >= npairs) t = npairs - 1;
    float4 xp = x[t];
    float a0 = xp.x * 0.5f + 0.5f, a1 = xp.y * 0.5f + 0.5f;
    float b0 = xp.z * 0.5f + 0.5f, b1 = xp.w * 0.5f + 0.5f;
    float accA[32], accB[32];
#pragma unroll
    for (int l = 0; l < HG_LEVELS; ++l) {
        const int res = 16 << l;
        const float scale = (float)res - 1.0f;
        float pA0 = a0 * scale + 0.5f, pA1 = a1 * scale + 0.5f;
        float pB0 = b0 * scale + 0.5f, pB1 = b1 * scale + 0.5f;
        float gA0 = floorf(pA0), gA1 = floorf(pA1), gB0 = floorf(pB0), gB1 = floorf(pB1);
        float fA0 = pA0 - gA0, fA1 = pA1 - gA1, fB0 = pB0 - gB0, fB1 = pB1 - gB1;
        uint32_t cA0 = (uint32_t)(int)gA0, cA1 = (uint32_t)(int)gA1;
        uint32_t cB0 = (uint32_t)(int)gB0, cB1 = (uint32_t)(int)gB1;
        float wA0 = fA0 * fA0 * (3.0f - 2.0f * fA0), wA1 = fA1 * fA1 * (3.0f - 2.0f * fA1);
        float wB0 = fB0 * fB0 * (3.0f - 2.0f * fB0), wB1 = fB1 * fB1 * (3.0f - 2.0f * fB1);
        uint32_t iA[4], iB[4];
        if (l <= 5) {
            uint32_t mask = (uint32_t)res * (uint32_t)res - 1u;
            uint32_t bA0 = cA1 * (uint32_t)res, bA1 = (cA1 + 1u) * (uint32_t)res;
            uint32_t bB0 = cB1 * (uint32_t)res, bB1 = (cB1 + 1u) * (uint32_t)res;
            iA[0]=(cA0+bA0)&mask; iA[1]=(cA0+1u+bA0)&mask; iA[2]=(cA0+bA1)&mask; iA[3]=(cA0+1u+bA1)&mask;
            iB[0]=(cB0+bB0)&mask; iB[1]=(cB0+1u+bB0)&mask; iB[2]=(cB0+bB1)&mask; iB[3]=(cB0+1u+bB1)&mask;
        } else {
            uint32_t hA0 = cA1*HG_PRIME1, hA1 = (cA1+1u)*HG_PRIME1;
            uint32_t hB0 = cB1*HG_PRIME1, hB1 = (cB1+1u)*HG_PRIME1;
            iA[0]=(cA0^hA0)&(HG_T-1u); iA[1]=((cA0+1u)^hA0)&(HG_T-1u);
            iA[2]=(cA0^hA1)&(HG_T-1u); iA[3]=((cA0+1u)^hA1)&(HG_T-1u);
            iB[0]=(cB0^hB0)&(HG_T-1u); iB[1]=((cB0+1u)^hB0)&(HG_T-1u);
            iB[2]=(cB0^hB1)&(HG_T-1u); iB[3]=((cB0+1u)^hB1)&(HG_T-1u);
        }
        const float2* tl = (const float2*)(table + (size_t)l * (size_t)HG_T * 2u);
        float2 fa[4], fb[4];
#pragma unroll
        for (int c = 0; c < 4; ++c) fa[c] = tl[iA[c]];
#pragma unroll
        for (int c = 0; c < 4; ++c) fb[c] = tl[iB[c]];
        float wwA[4] = {(1.f-wA0)*(1.f-wA1), wA0*(1.f-wA1), (1.f-wA0)*wA1, wA0*wA1};
        float wwB[4] = {(1.f-wB0)*(1.f-wB1), wB0*(1.f-wB1), (1.f-wB0)*wB1, wB0*wB1};
        float sAx=0.f,sAy=0.f,sBx=0.f,sBy=0.f;
#pragma unroll
        for (int c = 0; c < 4; ++c) {
            sAx += wwA[c]*fa[c].x; sAy += wwA[c]*fa[c].y;
            sBx += wwB[c]*fb[c].x; sBy += wwB[c]*fb[c].y;
        }
        accA[2*l]=sAx; accA[2*l+1]=sAy; accB[2*l]=sBx; accB[2*l+1]=sBy;
        if (l >= 5 && l < HG_LEVELS - 1) __syncthreads();
    }
    float4* oA = (float4*)(out + (size_t)(2*t+0)*32u);
    float4* oB = (float4*)(out + (size_t)(2*t+1)*32u);
#pragma unroll
    for (int j = 0; j < 8; ++j) oA[j] = make_float4(accA[4*j],accA[4*j+1],accA[4*j+2],accA[4*j+3]);
#pragma unroll
    for (int j = 0; j < 8; ++j) oB[j] = make_float4(accB[4*j],accB[4*j+1],accB[4*j+2],accB[4*j+3]);
}

extern "C" void kernel_launch(void* const* d_in, const int* in_sizes, int n_in,
                              void* d_out, int out_size, void* d_ws, size_t ws_size,
                              hipStream_t stream) {
    const float* x = (const float*)d_in[0];
    const float* table = (const float*)d_in[1];
    float* out = (float*)d_out;

    int npts = in_sizes[0] / 2;                       // 524288
    size_t need = (size_t)HG_LEVELS * (size_t)npts * 2u * sizeof(float);  // 64 MB

    if (ws_size >= need && d_ws != nullptr) {
        float* scratch = (float*)d_ws;
        int CH = (npts + 511) / 512;                  // 1024 chunks per level
        int grid1 = 16 * CH;                          // (8 xcd) x (2 levels) x CH
        hg_gather_kernel<<<grid1, 256, 0, stream>>>(x, table, scratch, npts, CH);
        hg_transpose_kernel<<<CH, 256, 0, stream>>>(scratch, out, npts);
    } else {
        int npairs = npts / 2;
        int grid = (npairs + 255) / 256;
        hg_fallback_kernel<<<grid, 256, 0, stream>>>((const float4*)x, table, out, npairs);
    }
}